// Round 3
// baseline (336.057 us; speedup 1.0000x reference)
//
#include <hip/hip_runtime.h>

#define IMG_W 512
#define IMG_H 512
#define N_IMG 48            // 16 batch * 3 channels
#define TILE_W 64
#define TILE_H 32
#define RAD 5
#define KS 11
#define HALO_H (TILE_H + 2*RAD)   // 42
#define W4 (TILE_W/4)             // 16 float4 per tile row
#define NBLOCKS (8*16*48)         // 6144

typedef float f32x2 __attribute__((ext_vector_type(2)));
typedef float f32x4 __attribute__((ext_vector_type(4)));

__global__ void ssim_zero_acc(double* acc) {
    if (threadIdx.x == 0) { acc[0] = 0.0; ((unsigned int*)(acc + 1))[0] = 0u; }
}

__device__ inline float ssim_rcp(float x) { return __builtin_amdgcn_rcpf(x); }

__global__ __launch_bounds__(256, 3)
void ssim_main(const float* __restrict__ pred, const float* __restrict__ targ,
               double* __restrict__ acc, float* __restrict__ out)
{
    // 5 hconv arrays [arr][halo_row][col4], float4 -> 53,760 B -> 3 blocks/CU
    __shared__ f32x4 s4[5][HALO_H][W4];
    __shared__ float wave_part[4];

    // Gaussian weights (sigma=1.5, normalized)
    float wt[KS];
    {
        float ssum = 0.f;
        #pragma unroll
        for (int i = 0; i < KS; ++i) {
            const float d = (float)(i - RAD);
            wt[i] = expf(-d * d / 4.5f);
            ssum += wt[i];
        }
        #pragma unroll
        for (int i = 0; i < KS; ++i) wt[i] /= ssum;
    }

    const int tid  = threadIdx.x;
    const int col0 = blockIdx.x * TILE_W;
    const int row0 = blockIdx.y * TILE_H;
    const bool edge = (blockIdx.x == 0) || (blockIdx.x == IMG_W / TILE_W - 1);
    const long img = blockIdx.z;
    const float* __restrict__ p = pred + img * (long)(IMG_H * IMG_W);
    const float* __restrict__ t = targ + img * (long)(IMG_H * IMG_W);

    // ---- Phase 1: horizontal 11-tap conv, packed-f32 polyphase ----
    // item -> (halo row rl, col4 c4); outputs cols col0+4c4+k, k=0..3
    // rp[0..19] = row[base .. base+19], base = col0+4c4-8 (16B aligned).
    // o[k] = sum_j wt[j] * rp[k+j+3].
    for (int idx = tid; idx < HALO_H * W4; idx += 256) {
        const int rl = idx >> 4;
        const int c4 = idx & 15;
        const int grow = row0 - RAD + rl;
        f32x4 st[5];
        #pragma unroll
        for (int a = 0; a < 5; ++a) st[a] = (f32x4)(0.f);

        if (grow >= 0 && grow < IMG_H) {
            const float* __restrict__ prow = p + (long)grow * IMG_W;
            const float* __restrict__ trow = t + (long)grow * IMG_W;
            const int base = col0 + c4 * 4 - 8;

            float rp[20] __attribute__((aligned(16)));
            float rt[20] __attribute__((aligned(16)));
            if (!edge) {
                #pragma unroll
                for (int g = 0; g < 5; ++g) {
                    *(float4*)&rp[4 * g] = *(const float4*)&prow[base + 4 * g];
                    *(float4*)&rt[4 * g] = *(const float4*)&trow[base + 4 * g];
                }
            } else {
                #pragma unroll
                for (int g = 0; g < 5; ++g) {
                    const int gc = base + 4 * g;
                    if (gc >= 0 && gc + 4 <= IMG_W) {
                        *(float4*)&rp[4 * g] = *(const float4*)&prow[gc];
                        *(float4*)&rt[4 * g] = *(const float4*)&trow[gc];
                    } else {
                        #pragma unroll
                        for (int e = 0; e < 4; ++e) {
                            const int c = gc + e;
                            const bool ok = (c >= 0) && (c < IMG_W);
                            rp[4 * g + e] = ok ? prow[c] : 0.f;
                            rt[4 * g + e] = ok ? trow[c] : 0.f;
                        }
                    }
                }
            }
            // aligned pairs P2[i]=(rp[2i],rp[2i+1]); shifted SP[i]=(rp[2i+1],rp[2i+2])
            f32x2 P2[10], T2[10];
            #pragma unroll
            for (int i = 0; i < 10; ++i) {
                P2[i] = (f32x2){rp[2 * i], rp[2 * i + 1]};
                T2[i] = (f32x2){rt[2 * i], rt[2 * i + 1]};
            }
            f32x2 SP[8], ST[8];
            #pragma unroll
            for (int i = 1; i < 8; ++i) {
                SP[i] = (f32x2){rp[2 * i + 1], rp[2 * i + 2]};
                ST[i] = (f32x2){rt[2 * i + 1], rt[2 * i + 2]};
            }
            f32x2 PP[10], TT[10], PT[10], SPP[8], STT[8], SPT[8];
            #pragma unroll
            for (int i = 2; i < 8; ++i) {
                PP[i] = P2[i] * P2[i];
                TT[i] = T2[i] * T2[i];
                PT[i] = P2[i] * T2[i];
            }
            #pragma unroll
            for (int i = 1; i < 8; ++i) {
                SPP[i] = SP[i] * SP[i];
                STT[i] = ST[i] * ST[i];
                SPT[i] = SP[i] * ST[i];
            }
            // o01 = sum_{i=0..5} wt[2i]*SHIFT[i+1] + sum_{i=0..4} wt[2i+1]*ALIGN[i+2]
            // o23 = sum_{i=0..5} wt[2i]*SHIFT[i+2] + sum_{i=0..4} wt[2i+1]*ALIGN[i+3]
            f32x2 o01[5], o23[5];
            #pragma unroll
            for (int a = 0; a < 5; ++a) { o01[a] = (f32x2)(0.f); o23[a] = (f32x2)(0.f); }
            #pragma unroll
            for (int i = 0; i < 6; ++i) {
                const float w = wt[2 * i];
                o01[0] += w * SP [i + 1];  o23[0] += w * SP [i + 2];
                o01[1] += w * ST [i + 1];  o23[1] += w * ST [i + 2];
                o01[2] += w * SPP[i + 1];  o23[2] += w * SPP[i + 2];
                o01[3] += w * STT[i + 1];  o23[3] += w * STT[i + 2];
                o01[4] += w * SPT[i + 1];  o23[4] += w * SPT[i + 2];
            }
            #pragma unroll
            for (int i = 0; i < 5; ++i) {
                const float w = wt[2 * i + 1];
                o01[0] += w * P2[i + 2];   o23[0] += w * P2[i + 3];
                o01[1] += w * T2[i + 2];   o23[1] += w * T2[i + 3];
                o01[2] += w * PP[i + 2];   o23[2] += w * PP[i + 3];
                o01[3] += w * TT[i + 2];   o23[3] += w * TT[i + 3];
                o01[4] += w * PT[i + 2];   o23[4] += w * PT[i + 3];
            }
            #pragma unroll
            for (int a = 0; a < 5; ++a)
                st[a] = (f32x4){o01[a].x, o01[a].y, o23[a].x, o23[a].y};
        }
        #pragma unroll
        for (int a = 0; a < 5; ++a) s4[a][rl][c4] = st[a];
    }
    __syncthreads();

    // ---- Phase 2: vertical 11-tap conv, 4 rows x 2 cols per thread, packed ----
    const int c2    = tid & 31;       // column pair 0..31
    const int rg    = tid >> 5;       // row group 0..7
    const int rbase = rg * 4;         // output rows rbase..rbase+3

    f32x2 va[4][5];
    #pragma unroll
    for (int r = 0; r < 4; ++r)
        #pragma unroll
        for (int a = 0; a < 5; ++a) va[r][a] = (f32x2)(0.f);

    #pragma unroll
    for (int jj = 0; jj < 14; ++jj) {
        f32x2 v[5];
        #pragma unroll
        for (int a = 0; a < 5; ++a)
            v[a] = ((const f32x2*)&s4[a][rbase + jj][0])[c2];
        #pragma unroll
        for (int r = 0; r < 4; ++r) {
            const int jr = jj - r;
            if (jr >= 0 && jr <= 10) {
                const float w = wt[jr];
                #pragma unroll
                for (int a = 0; a < 5; ++a) va[r][a] += w * v[a];
            }
        }
    }

    const float C1 = 1e-4f, C2 = 9e-4f;
    float lsum = 0.f;
    #pragma unroll
    for (int r = 0; r < 4; ++r) {
        const f32x2 m1 = va[r][0], m2 = va[r][1];
        const f32x2 epp = va[r][2], ett = va[r][3], ept = va[r][4];
        const f32x2 m1s = m1 * m1, m2s = m2 * m2, m12 = m1 * m2;
        const f32x2 num = (2.f * m12 + C1) * (2.f * (ept - m12) + C2);
        const f32x2 den = (m1s + m2s + C1) * ((epp - m1s) + (ett - m2s) + C2);
        lsum += num.x * ssim_rcp(den.x);
        lsum += num.y * ssim_rcp(den.y);
    }

    // ---- Block reduction -> one double atomic; last block finalizes ----
    #pragma unroll
    for (int off = 32; off > 0; off >>= 1)
        lsum += __shfl_down(lsum, off, 64);
    const int wave = tid >> 6;
    const int lane = tid & 63;
    if (lane == 0) wave_part[wave] = lsum;
    __syncthreads();
    if (tid == 0) {
        const float bs = wave_part[0] + wave_part[1] + wave_part[2] + wave_part[3];
        atomicAdd(acc, (double)bs);
        __threadfence();                               // release our contribution
        unsigned int* cnt = (unsigned int*)(acc + 1);
        const unsigned int old = atomicAdd(cnt, 1u);
        if (old == NBLOCKS - 1) {                      // all contributions visible
            const double tot = atomicAdd(acc, 0.0);    // device-coherent read
            const double n = (double)N_IMG * (double)IMG_H * (double)IMG_W;
            out[0] = (float)(1.0 - tot / n);
        }
    }
}

extern "C" void kernel_launch(void* const* d_in, const int* in_sizes, int n_in,
                              void* d_out, int out_size, void* d_ws, size_t ws_size,
                              hipStream_t stream) {
    const float* pred = (const float*)d_in[0];
    const float* targ = (const float*)d_in[1];
    float* out  = (float*)d_out;
    double* acc = (double*)d_ws;   // [0]=sum (double), [1]=block counter (uint)

    hipLaunchKernelGGL(ssim_zero_acc, dim3(1), dim3(1), 0, stream, acc);
    dim3 grid(IMG_W / TILE_W, IMG_H / TILE_H, N_IMG);   // (8, 16, 48)
    hipLaunchKernelGGL(ssim_main, grid, dim3(256), 0, stream, pred, targ, acc, out);
}